// Round 8
// baseline (226.665 us; speedup 1.0000x reference)
//
#include <hip/hip_runtime.h>

// Conv2d 3x3 pad1 stride1, x[1,256,224,224] f32, w[256,256,3,3] f32 -> out[256,224,224] f32
// Implicit GEMM: M=256 (co), N=50176 (h*224+w), K=2304 (tap-major: k = (dh*3+dw)*256 + ci)
// R8: barrier-free wave-private pipeline (R7) + EXPLICIT waitcnt discipline:
//   - each half-iter stages exactly 12 global_load_lds (8 A dup + 4 B) -> <=24 outstanding
//   - s_waitcnt vmcnt(12) before consuming a buffer (oldest 12 = that buffer)
//   - s_waitcnt lgkmcnt(0) after frag ds_reads, BEFORE re-staging that buffer (WAR-safe,
//     and the side-effecting waitcnt pins the scheduler: stage can't hoist above reads)
//   - tail: vmcnt(12) then vmcnt(0). Zero __syncthreads in the K-loop.
// 2 waves/block, wave-tile 128(M)x64(N), BK=32, 48KB LDS -> 3 blocks/CU.

#define H 224
#define W 224
#define NPOS (H*W)          // 50176
#define CI 256
#define CO 256
#define KDIM 2304
#define HP 226              // padded
#define XP_ELEMS (HP*HP*CI) // 13,075,456 shorts
#define AP_ELEMS (CO*KDIM)  // 589,824 shorts

// s_waitcnt imm (gfx9): vmcnt[3:0]=bits3:0, expcnt=bits6:4, lgkmcnt=bits11:8, vmcnt[5:4]=bits15:14
#define WAIT_VM12 0x0F7C    // vmcnt=12, expcnt=7 (no wait), lgkmcnt=15 (no wait)
#define WAIT_VM0  0x0F70    // vmcnt=0,  expcnt=7, lgkmcnt=15
#define WAIT_LGKM0 0xC07F   // vmcnt=63 (no wait), expcnt=7, lgkmcnt=0

typedef __bf16 bf16x8 __attribute__((ext_vector_type(8)));
typedef float f32x4 __attribute__((ext_vector_type(4)));

__device__ __forceinline__ unsigned short f2bf(float f) {
    unsigned int u = __float_as_uint(f);
    u += 0x7fff + ((u >> 16) & 1);   // round-to-nearest-even
    return (unsigned short)(u >> 16);
}

__device__ __forceinline__ void load_lds16(const unsigned short* g, unsigned short* l) {
    __builtin_amdgcn_global_load_lds(
        (const __attribute__((address_space(1))) void*)g,
        (__attribute__((address_space(3))) void*)l,
        16, 0, 0);
}

// ---- fused: weight f32 [co][ci][3][3] -> bf16 A'[co][tap*256+ci]  (blocks 0..2303)
//      + zero the 1-px border of Xp [226][226][256]                 (blocks 2304..3203)
__global__ void prologue_kernel(const float* __restrict__ w, unsigned short* __restrict__ ap,
                                unsigned short* __restrict__ xp) {
    if (blockIdx.x < AP_ELEMS / 256) {
        int o = blockIdx.x * 256 + threadIdx.x;  // o = co*2304 + tap*256 + ci
        int co = o / KDIM;
        int rem = o - co * KDIM;
        int tap = rem >> 8;
        int ci = rem & 255;
        ap[o] = f2bf(w[(co * CI + ci) * 9 + tap]);
    } else {
        int idx = (blockIdx.x - AP_ELEMS / 256) * 256 + threadIdx.x;  // 230400 total
        int hp, wp, ci;
        if (idx < 2 * HP * CI) {                 // rows 0 and 225
            int r = idx / (HP * CI);
            int rem = idx - r * (HP * CI);
            hp = r * (HP - 1);
            wp = rem / CI;
            ci = rem & (CI - 1);
        } else {
            int i2 = idx - 2 * HP * CI;          // cols 0 and 225, h=1..224
            int side = i2 / (H * CI);
            int rem = i2 - side * (H * CI);
            hp = 1 + rem / CI;
            wp = side * (HP - 1);
            ci = rem & (CI - 1);
        }
        xp[(hp * HP + wp) * CI + ci] = 0;
    }
}

// ---- input: f32 [ci][224][224] -> bf16 padded NHWC Xp[226][226][256] interior ----
__global__ void xtrans_kernel(const float* __restrict__ x, unsigned short* __restrict__ xp) {
    __shared__ unsigned short tile[64][66];
    const unsigned int pBase = blockIdx.x * 64;
    const unsigned int ciBase = blockIdx.y * 64;
    const unsigned int t = threadIdx.x;
    {
        const unsigned int p_l = t & 63;
        const unsigned int c0 = t >> 6;          // 0..3
#pragma unroll
        for (int i = 0; i < 16; ++i) {
            const unsigned int ci_l = c0 + i * 4;
            tile[ci_l][p_l] = f2bf(x[(ciBase + ci_l) * NPOS + pBase + p_l]);
        }
    }
    __syncthreads();
    {
        const unsigned int ci_l = t & 63;
        const unsigned int p0 = t >> 6;          // 0..3
#pragma unroll
        for (int i = 0; i < 16; ++i) {
            const unsigned int p_l = p0 + i * 4;
            const unsigned int p = pBase + p_l;
            const unsigned int hi = p / W;
            const unsigned int wi = p - hi * W;
            xp[((hi + 1) * HP + (wi + 1)) * CI + ciBase + ci_l] = tile[ci_l][p_l];
        }
    }
}

// ---- implicit GEMM, barrier-free + explicit vmcnt: 2 waves, wave-tile 128Mx64N ----
// Swizzle (4 chunks of 8 shorts per 32-short row):
//   store: lane l -> row (l>>2), slot l&3, source chunk (l&3)^((l>>2)&3)
//   read : chunk quad of row r lives at slot quad^(r&3); r&3 == ln15&3
__global__ __launch_bounds__(128, 2) void gemm_conv_kernel(
    const unsigned short* __restrict__ Ap,   // [256][2304] bf16
    const unsigned short* __restrict__ Xp,   // [226][226][256] bf16
    float* __restrict__ out)                 // [256][50176]
{
    __shared__ unsigned short Als[2][2][4096];   // [wave][buf][128 rows x 32]
    __shared__ unsigned short Bls[2][2][2048];   // [wave][buf][ 64 rows x 32]

    const int tid = threadIdx.x;
    const int Nb = blockIdx.x;               // 0..391
    const int Mb = blockIdx.y;               // 0..1
    const int wave = tid >> 6;               // 0..1
    const int lane = tid & 63;
    const int ln15 = lane & 15;
    const int quad = lane >> 4;
    const int sw = ln15 & 3;

    // ---- staging source pointers ----
    const int l2 = lane >> 2;                // 0..15
    const int c4 = (lane & 3) ^ (l2 & 3);    // swizzled source chunk

    // A: instr j (0..7) stages rows j*16 .. j*16+15 of the block's 128 M-rows
    const unsigned short* a_base = Ap + (Mb * 128 + l2) * KDIM + c4 * 8;   // + j*16*KDIM + kc*32

    // B: instr j (0..3) stages rows j*16 .. j*16+15 of this wave's 64 N-cols
    const unsigned short* b_src[4];
#pragma unroll
    for (int j = 0; j < 4; ++j) {
        unsigned int p = Nb * 128 + wave * 64 + j * 16 + l2;
        unsigned int hi = p / W, wi = p - hi * W;
        b_src[j] = Xp + (hi * HP + wi) * CI + c4 * 8;      // + tap/ci offset
    }

    f32x4 acc[8][4];
#pragma unroll
    for (int mi = 0; mi < 8; ++mi)
#pragma unroll
        for (int ni = 0; ni < 4; ++ni)
            acc[mi][ni] = (f32x4){0.f, 0.f, 0.f, 0.f};

    // stage K-chunk kc into private buffer buf: exactly 12 global_load_lds
    auto stage = [&](int kc, int buf) {
        const int tap = kc >> 3;             // 0..8
        const int dh = tap / 3, dw = tap - dh * 3;
        const int boff = (dh * HP + dw) * CI + (kc & 7) * 32;
        const int aoff = kc * 32;
#pragma unroll
        for (int j = 0; j < 8; ++j)
            load_lds16(a_base + j * (16 * KDIM) + aoff, &Als[wave][buf][j * 512]);
#pragma unroll
        for (int j = 0; j < 4; ++j)
            load_lds16(b_src[j] + boff, &Bls[wave][buf][j * 512]);
    };

    bf16x8 af[8], bfr[4];
    auto frags = [&](int buf) {
#pragma unroll
        for (int mi = 0; mi < 8; ++mi)
            af[mi] = *(const bf16x8*)&Als[wave][buf][(mi * 16 + ln15) * 32 + ((quad ^ sw) * 8)];
#pragma unroll
        for (int ni = 0; ni < 4; ++ni)
            bfr[ni] = *(const bf16x8*)&Bls[wave][buf][(ni * 16 + ln15) * 32 + ((quad ^ sw) * 8)];
    };
    auto domfma = [&]() {
#pragma unroll
        for (int mi = 0; mi < 8; ++mi)
#pragma unroll
            for (int ni = 0; ni < 4; ++ni)
                acc[mi][ni] = __builtin_amdgcn_mfma_f32_16x16x32_bf16(
                    af[mi], bfr[ni], acc[mi][ni], 0, 0, 0);
    };

    stage(0, 0);                             // 12 outstanding
    stage(1, 1);                             // 24 outstanding
    for (int kc = 0; kc < 70; kc += 2) {
        __builtin_amdgcn_s_waitcnt(WAIT_VM12);   // buf0 (oldest 12) landed
        frags(0);
        __builtin_amdgcn_s_waitcnt(WAIT_LGKM0);  // frags in VGPRs -> buf0 overwrite safe
        stage(kc + 2, 0);                    // back to 24 outstanding
        domfma();
        __builtin_amdgcn_s_waitcnt(WAIT_VM12);   // buf1 landed
        frags(1);
        __builtin_amdgcn_s_waitcnt(WAIT_LGKM0);
        stage(kc + 3, 1);                    // kc<=68 -> kc+3<=71
        domfma();
    }
    // kc = 70, 71 (no more staging)
    __builtin_amdgcn_s_waitcnt(WAIT_VM12);       // stage(70) landed
    frags(0);
    domfma();
    __builtin_amdgcn_s_waitcnt(WAIT_VM0);        // stage(71) landed
    frags(1);
    domfma();

    // epilogue: C/D layout col = lane&15 (n=p), row = quad*4 + reg (m=co)
    const int pcol = Nb * 128 + wave * 64 + ln15;
    const int corow = Mb * 128 + quad * 4;
#pragma unroll
    for (int mi = 0; mi < 8; ++mi)
#pragma unroll
        for (int ni = 0; ni < 4; ++ni)
#pragma unroll
            for (int r = 0; r < 4; ++r)
                out[(corow + mi * 16 + r) * NPOS + pcol + ni * 16] = acc[mi][ni][r];
}

extern "C" void kernel_launch(void* const* d_in, const int* in_sizes, int n_in,
                              void* d_out, int out_size, void* d_ws, size_t ws_size,
                              hipStream_t stream) {
    const float* x = (const float*)d_in[0];       // [1,256,224,224]
    const float* w = (const float*)d_in[1];       // [256,256,3,3]
    float* out = (float*)d_out;                   // [256,224,224]

    unsigned short* xp = (unsigned short*)d_ws;        // 13,075,456 shorts
    unsigned short* ap = xp + XP_ELEMS;                // 589,824 shorts

    prologue_kernel<<<AP_ELEMS / 256 + 900, 256, 0, stream>>>(w, ap, xp);
    xtrans_kernel<<<dim3(NPOS / 64, CI / 64), 256, 0, stream>>>(x, xp);
    gemm_conv_kernel<<<dim3(NPOS / 128, CO / 128), 128, 0, stream>>>(ap, xp, out);
}